// Round 9
// baseline (342.387 us; speedup 1.0000x reference)
//
#include <hip/hip_runtime.h>

#define N_NODES   100000
#define N_EDGES   1600000
#define IN_DIM    128
#define HID_DIM   64
#define N_CLASSES 40

#define NBUCK 782          // ceil(100000 / 128) coarse buckets, bucket = row >> 7
#define BCAP  2816         // bucket capacity incl. pad-to-8
#define EPB   6400         // edges per block in pass A
#define PBLK  1024         // part_a block size
#define RPW   8            // rows per wave in spmm (pipelined)

typedef __attribute__((ext_vector_type(8))) short bf16x8;
typedef __attribute__((ext_vector_type(4))) float f32x4;

__device__ inline short f2bf(float f) {
    unsigned u = __float_as_uint(f);
    unsigned r = (u + 0x7FFFu + ((u >> 16) & 1u)) >> 16;   // RNE
    return (short)r;
}
__device__ inline float bflo(unsigned w) { return __uint_as_float(w << 16); }
__device__ inline float bfhi(unsigned w) { return __uint_as_float(w & 0xFFFF0000u); }

// ---------------- weight prep ----------------
// W1t bf16 [64][128]; Mt = (W2@Wc)^T bf16 [64][64] (rows 40..63 zero); bv = b2@Wc fp32 [40]
__global__ __launch_bounds__(256) void prep_weights(const float* __restrict__ W1,
                                                    const float* __restrict__ W2,
                                                    const float* __restrict__ Wc,
                                                    const float* __restrict__ b2,
                                                    short* __restrict__ W1t,
                                                    short* __restrict__ Mt,
                                                    float* __restrict__ bv) {
    for (int i = blockIdx.x * 256 + threadIdx.x; i < IN_DIM * HID_DIM; i += gridDim.x * 256) {
        int n = i >> 7, k = i & 127;
        W1t[i] = f2bf(W1[k * HID_DIM + n]);
    }
    if (blockIdx.x == 0) {
        for (int idx = threadIdx.x; idx < HID_DIM * HID_DIM; idx += 256) {
            int n = idx >> 6, i = idx & 63;        // Mt[n][i] = M[i][n] = sum_j W2[i][j]*Wc[j][n]
            float acc = 0.f;
            if (n < N_CLASSES)
                for (int j = 0; j < HID_DIM; ++j)
                    acc = fmaf(W2[i * HID_DIM + j], Wc[j * N_CLASSES + n], acc);
            Mt[n * HID_DIM + i] = f2bf(acc);
        }
        for (int n = threadIdx.x; n < N_CLASSES; n += 256) {
            float acc = 0.f;
            for (int j = 0; j < HID_DIM; ++j)
                acc = fmaf(b2[j], Wc[j * N_CLASSES + n], acc);
            bv[n] = acc;
        }
    }
}

// ---------------- GEMM1 (MFMA): hbf[n,64] = bf16(x[n,128] @ W1 + b1) ----------------
__global__ __launch_bounds__(256) void gemm1_mfma(const float* __restrict__ x,
                                                  const short* __restrict__ W1t,
                                                  const float* __restrict__ b1,
                                                  unsigned short* __restrict__ out) {
    int wave = threadIdx.x >> 6;
    int lane = threadIdx.x & 63;
    int node0 = blockIdx.x * 64 + wave * 16;
    if (node0 >= N_NODES) return;
    int m = lane & 15;
    int q = lane >> 4;
    const float* xrow = x + (size_t)(node0 + m) * IN_DIM;
    f32x4 acc0 = {0,0,0,0}, acc1 = {0,0,0,0}, acc2 = {0,0,0,0}, acc3 = {0,0,0,0};
#pragma unroll
    for (int kb = 0; kb < 4; ++kb) {
        int k0 = kb * 32 + q * 8;
        float4 a0 = *(const float4*)(xrow + k0);
        float4 a1 = *(const float4*)(xrow + k0 + 4);
        bf16x8 af;
        af[0]=f2bf(a0.x); af[1]=f2bf(a0.y); af[2]=f2bf(a0.z); af[3]=f2bf(a0.w);
        af[4]=f2bf(a1.x); af[5]=f2bf(a1.y); af[6]=f2bf(a1.z); af[7]=f2bf(a1.w);
        bf16x8 bf0 = *(const bf16x8*)(W1t + ( 0 + m) * IN_DIM + k0);
        bf16x8 bf1 = *(const bf16x8*)(W1t + (16 + m) * IN_DIM + k0);
        bf16x8 bf2 = *(const bf16x8*)(W1t + (32 + m) * IN_DIM + k0);
        bf16x8 bf3 = *(const bf16x8*)(W1t + (48 + m) * IN_DIM + k0);
        acc0 = __builtin_amdgcn_mfma_f32_16x16x32_bf16(af, bf0, acc0, 0, 0, 0);
        acc1 = __builtin_amdgcn_mfma_f32_16x16x32_bf16(af, bf1, acc1, 0, 0, 0);
        acc2 = __builtin_amdgcn_mfma_f32_16x16x32_bf16(af, bf2, acc2, 0, 0, 0);
        acc3 = __builtin_amdgcn_mfma_f32_16x16x32_bf16(af, bf3, acc3, 0, 0, 0);
    }
    f32x4 accs[4] = {acc0, acc1, acc2, acc3};
#pragma unroll
    for (int t = 0; t < 4; ++t) {
        float bias = b1[t * 16 + m];
#pragma unroll
        for (int r = 0; r < 4; ++r) {
            int node = node0 + q * 4 + r;            // C/D: col=lane&15, row=q*4+r
            out[(size_t)node * HID_DIM + t * 16 + m] = (unsigned short)f2bf(accs[t][r] + bias);
        }
    }
}

// ---------------- GEMM2u (MFMA): u[n,64] = bf16(relu(hbf[n,64]) @ M)  (no bias) ----------------
__global__ __launch_bounds__(256) void gemm2u_mfma(const unsigned short* __restrict__ h,
                                                   const short* __restrict__ Mt,
                                                   unsigned short* __restrict__ out) {
    int wave = threadIdx.x >> 6;
    int lane = threadIdx.x & 63;
    int node0 = blockIdx.x * 64 + wave * 16;
    if (node0 >= N_NODES) return;
    int m = lane & 15;
    int q = lane >> 4;
    const unsigned short* hrow = h + (size_t)(node0 + m) * HID_DIM;
    f32x4 acc0 = {0,0,0,0}, acc1 = {0,0,0,0}, acc2 = {0,0,0,0}, acc3 = {0,0,0,0};
#pragma unroll
    for (int kb = 0; kb < 2; ++kb) {
        int k0 = kb * 32 + q * 8;
        bf16x8 af = *(const bf16x8*)(hrow + k0);
#pragma unroll
        for (int j = 0; j < 8; ++j)
            af[j] = ((unsigned short)af[j] & 0x8000u) ? 0 : af[j];   // bf16 ReLU
        bf16x8 bf0 = *(const bf16x8*)(Mt + ( 0 + m) * HID_DIM + k0);
        bf16x8 bf1 = *(const bf16x8*)(Mt + (16 + m) * HID_DIM + k0);
        bf16x8 bf2 = *(const bf16x8*)(Mt + (32 + m) * HID_DIM + k0);
        bf16x8 bf3 = *(const bf16x8*)(Mt + (48 + m) * HID_DIM + k0);
        acc0 = __builtin_amdgcn_mfma_f32_16x16x32_bf16(af, bf0, acc0, 0, 0, 0);
        acc1 = __builtin_amdgcn_mfma_f32_16x16x32_bf16(af, bf1, acc1, 0, 0, 0);
        acc2 = __builtin_amdgcn_mfma_f32_16x16x32_bf16(af, bf2, acc2, 0, 0, 0);
        acc3 = __builtin_amdgcn_mfma_f32_16x16x32_bf16(af, bf3, acc3, 0, 0, 0);
    }
    f32x4 accs[4] = {acc0, acc1, acc2, acc3};
#pragma unroll
    for (int t = 0; t < 4; ++t) {
#pragma unroll
        for (int r = 0; r < 4; ++r) {
            int node = node0 + q * 4 + r;
            out[(size_t)node * HID_DIM + t * 16 + m] = (unsigned short)f2bf(accs[t][r]);
        }
    }
}

// ---------------- Pass A v3: LDS-staged bucket sort, coalesced write-out ----------------
__global__ __launch_bounds__(PBLK) void part_a(const int* __restrict__ erow,
                                               const int* __restrict__ ecol,
                                               const float* __restrict__ eval,
                                               int* __restrict__ bcnt,
                                               int2* __restrict__ tmp) {
    __shared__ int2 pay[EPB];
    __shared__ unsigned short sbuck[EPB];
    __shared__ int hist[NBUCK], lbase[NBUCK], cur[NBUCK], dofs[NBUCK], scan[NBUCK];
    int e0 = blockIdx.x * EPB;
    int tid = threadIdx.x;
    for (int i = tid; i < NBUCK; i += PBLK) { hist[i] = 0; cur[i] = 0; }
    __syncthreads();
    for (int i = tid; i < EPB; i += PBLK)
        atomicAdd(&hist[erow[e0 + i] >> 7], 1);
    __syncthreads();
    for (int i = tid; i < NBUCK; i += PBLK) {
        int n = hist[i];
        dofs[i] = i * BCAP + (n ? atomicAdd(&bcnt[i], n) : 0);
        scan[i] = n;
    }
    __syncthreads();
    for (int off = 1; off < NBUCK; off <<= 1) {
        int t = 0;
        if (tid < NBUCK && tid >= off) t = scan[tid - off];
        __syncthreads();
        if (tid < NBUCK) scan[tid] += t;
        __syncthreads();
    }
    if (tid < NBUCK) {
        lbase[tid] = scan[tid] - hist[tid];
        dofs[tid] -= lbase[tid];
    }
    __syncthreads();
    for (int i = tid; i < EPB; i += PBLK) {
        int e = e0 + i;
        int r = erow[e];
        int b = r >> 7;
        int p = lbase[b] + atomicAdd(&cur[b], 1);
        pay[p] = make_int2(((r & 127) << 17) | ecol[e], __float_as_int(eval[e]));
        sbuck[p] = (unsigned short)b;
    }
    __syncthreads();
    for (int p = tid; p < EPB; p += PBLK) {
        int b = sbuck[p];
        int dest = dofs[b] + p;
        if (dest < (b + 1) * BCAP)
            tmp[dest] = pay[p];
    }
}

// ---------------- Pass B: sort bucket by local row, pad each row to mult-of-8, col *= 64 ----------------
__global__ __launch_bounds__(256) void part_b(const int* __restrict__ bcnt,
                                              int2* __restrict__ tmp,
                                              int2* __restrict__ rowmeta) {
    __shared__ int2 ein[BCAP];
    __shared__ int2 eout[BCAP];
    __shared__ int hist[128], pad[128], basep[128], cur[128], scan[128];
    int b = blockIdx.x;
    int nb = bcnt[b]; if (nb > BCAP) nb = BCAP;
    for (int i = threadIdx.x; i < nb; i += 256) ein[i] = tmp[(size_t)b * BCAP + i];
    if (threadIdx.x < 128) { hist[threadIdx.x] = 0; cur[threadIdx.x] = 0; }
    __syncthreads();
    for (int i = threadIdx.x; i < nb; i += 256)
        atomicAdd(&hist[(ein[i].x >> 17) & 127], 1);
    __syncthreads();
    if (threadIdx.x < 128) {
        pad[threadIdx.x] = (hist[threadIdx.x] + 7) & ~7;
        scan[threadIdx.x] = pad[threadIdx.x];
    }
    __syncthreads();
    for (int off = 1; off < 128; off <<= 1) {
        int t = 0;
        if (threadIdx.x < 128 && threadIdx.x >= off) t = scan[threadIdx.x - off];
        __syncthreads();
        if (threadIdx.x < 128) scan[threadIdx.x] += t;
        __syncthreads();
    }
    if (threadIdx.x < 128) basep[threadIdx.x] = scan[threadIdx.x] - pad[threadIdx.x];
    __syncthreads();
    int ntot = scan[127]; if (ntot > BCAP) ntot = BCAP;
    for (int i = threadIdx.x; i < nb; i += 256) {
        int lr = (ein[i].x >> 17) & 127;
        int p = basep[lr] + atomicAdd(&cur[lr], 1);
        if (p < BCAP) eout[p] = make_int2((ein[i].x & 0x1FFFF) << 6, ein[i].y);
    }
    __syncthreads();
    if (threadIdx.x < 128) {
        int pe = basep[threadIdx.x] + pad[threadIdx.x];
        for (int p = basep[threadIdx.x] + hist[threadIdx.x]; p < pe && p < BCAP; ++p)
            eout[p] = make_int2(0, 0);
    }
    __syncthreads();
    for (int i = threadIdx.x; i < ntot; i += 256) tmp[(size_t)b * BCAP + i] = eout[i];
    if (threadIdx.x < 128) {
        int r = b * 128 + threadIdx.x;
        if (r < N_NODES)
            rowmeta[r] = make_int2(b * BCAP + basep[threadIdx.x], pad[threadIdx.x]);
    }
}

// ---------------- SpMM v4: 8 rows/wave, 1-row-lookahead software pipeline ----------------
// lane = (g = lane>>3: edge subgroup, dq = lane&7: dim octet); 16 B/lane dwordx4 gathers.
__global__ __launch_bounds__(256) void spmm_csr(const int2* __restrict__ rowmeta,
                                                const int2* __restrict__ ecv,
                                                const unsigned short* __restrict__ dense,
                                                unsigned short* __restrict__ out) {
    int wid = blockIdx.x * 4 + (threadIdx.x >> 6);
    int r0 = wid * RPW;                              // 3125 blocks * 4 waves * 8 rows = 100000
    int lane = threadIdx.x & 63;
    int g = lane >> 3, dq = lane & 7;
    int2 mymeta = rowmeta[r0 + (lane & 7)];
    int rs[RPW], dp[RPW];
    int2 em[RPW];
#pragma unroll
    for (int j = 0; j < RPW; ++j) {                  // all edge metadata issued upfront
        rs[j] = __shfl(mymeta.x, j);
        dp[j] = __shfl(mymeta.y, j);
        int idx = lane < dp[j] ? lane : (dp[j] > 0 ? dp[j] - 1 : 0);
        em[j] = ecv[rs[j] + idx];
    }
    uint4 d[2][8];
#pragma unroll
    for (int t = 0; t < 8; ++t)                      // prologue: gathers for row 0
        if (t < (dp[0] >> 3)) {
            int col = __shfl(em[0].x, t * 8 + g);
            d[0][t] = *(const uint4*)(dense + (size_t)col + (dq << 3));
        }
#pragma unroll
    for (int j = 0; j < RPW; ++j) {
        if (j + 1 < RPW) {                           // issue row j+1's gathers before computing row j
#pragma unroll
            for (int t = 0; t < 8; ++t)
                if (t < (dp[j + 1] >> 3)) {
                    int col = __shfl(em[j + 1].x, t * 8 + g);
                    d[(j + 1) & 1][t] = *(const uint4*)(dense + (size_t)col + (dq << 3));
                }
        }
        float a0=0,a1=0,a2=0,a3=0,a4=0,a5=0,a6=0,a7=0;
#pragma unroll
        for (int t = 0; t < 8; ++t)
            if (t < (dp[j] >> 3)) {
                float v = __shfl(__int_as_float(em[j].y), t * 8 + g);
                uint4 dd = d[j & 1][t];
                a0 = fmaf(v, bflo(dd.x), a0);  a1 = fmaf(v, bfhi(dd.x), a1);
                a2 = fmaf(v, bflo(dd.y), a2);  a3 = fmaf(v, bfhi(dd.y), a3);
                a4 = fmaf(v, bflo(dd.z), a4);  a5 = fmaf(v, bfhi(dd.z), a5);
                a6 = fmaf(v, bflo(dd.w), a6);  a7 = fmaf(v, bfhi(dd.w), a7);
            }
        for (int e = rs[j] + 64; e < rs[j] + dp[j]; ++e) {   // rare tail deg>64
            int2 ee = ecv[e];
            if (g == 0) {
                float tv = __int_as_float(ee.y);
                uint4 td = *(const uint4*)(dense + (size_t)ee.x + (dq << 3));
                a0 = fmaf(tv, bflo(td.x), a0);  a1 = fmaf(tv, bfhi(td.x), a1);
                a2 = fmaf(tv, bflo(td.y), a2);  a3 = fmaf(tv, bfhi(td.y), a3);
                a4 = fmaf(tv, bflo(td.z), a4);  a5 = fmaf(tv, bfhi(td.z), a5);
                a6 = fmaf(tv, bflo(td.w), a6);  a7 = fmaf(tv, bfhi(td.w), a7);
            }
        }
#pragma unroll
        for (int off = 8; off < 64; off <<= 1) {
            a0 += __shfl_xor(a0, off); a1 += __shfl_xor(a1, off);
            a2 += __shfl_xor(a2, off); a3 += __shfl_xor(a3, off);
            a4 += __shfl_xor(a4, off); a5 += __shfl_xor(a5, off);
            a6 += __shfl_xor(a6, off); a7 += __shfl_xor(a7, off);
        }
        if (lane < 8) {
            uint4 o;
            o.x = (unsigned short)f2bf(a0) | ((unsigned)(unsigned short)f2bf(a1) << 16);
            o.y = (unsigned short)f2bf(a2) | ((unsigned)(unsigned short)f2bf(a3) << 16);
            o.z = (unsigned short)f2bf(a4) | ((unsigned)(unsigned short)f2bf(a5) << 16);
            o.w = (unsigned short)f2bf(a6) | ((unsigned)(unsigned short)f2bf(a7) << 16);
            *(uint4*)(out + (size_t)(r0 + j) * HID_DIM + lane * 8) = o;
        }
    }
}

// ---------------- SpMM+classify fused: logits = agg(u) + rowsum*bv + bc; log_softmax; fp32 out ----------------
__global__ __launch_bounds__(256) void spmm_cls(const int2* __restrict__ rowmeta,
                                                const int2* __restrict__ ecv,
                                                const unsigned short* __restrict__ dense,
                                                const float* __restrict__ bv,
                                                const float* __restrict__ bc,
                                                float* __restrict__ outF) {
    int wid = blockIdx.x * 4 + (threadIdx.x >> 6);
    int r0 = wid * RPW;
    int lane = threadIdx.x & 63;
    int g = lane >> 3, dq = lane & 7;
    float4 bv0 = {0,0,0,0}, bv1 = {0,0,0,0}, bc0 = {0,0,0,0}, bc1 = {0,0,0,0};
    if (dq < 5) {                                    // dims dq*8..dq*8+7 < 40
        bv0 = *(const float4*)(bv + dq * 8);  bv1 = *(const float4*)(bv + dq * 8 + 4);
        bc0 = *(const float4*)(bc + dq * 8);  bc1 = *(const float4*)(bc + dq * 8 + 4);
    }
    int2 mymeta = rowmeta[r0 + (lane & 7)];
    int rs[RPW], dp[RPW];
    int2 em[RPW];
#pragma unroll
    for (int j = 0; j < RPW; ++j) {
        rs[j] = __shfl(mymeta.x, j);
        dp[j] = __shfl(mymeta.y, j);
        int idx = lane < dp[j] ? lane : (dp[j] > 0 ? dp[j] - 1 : 0);
        em[j] = ecv[rs[j] + idx];
    }
    uint4 d[2][8];
#pragma unroll
    for (int t = 0; t < 8; ++t)
        if (t < (dp[0] >> 3)) {
            int col = __shfl(em[0].x, t * 8 + g);
            d[0][t] = *(const uint4*)(dense + (size_t)col + (dq << 3));
        }
#pragma unroll
    for (int j = 0; j < RPW; ++j) {
        if (j + 1 < RPW) {
#pragma unroll
            for (int t = 0; t < 8; ++t)
                if (t < (dp[j + 1] >> 3)) {
                    int col = __shfl(em[j + 1].x, t * 8 + g);
                    d[(j + 1) & 1][t] = *(const uint4*)(dense + (size_t)col + (dq << 3));
                }
        }
        float a0=0,a1=0,a2=0,a3=0,a4=0,a5=0,a6=0,a7=0, asum=0;
#pragma unroll
        for (int t = 0; t < 8; ++t)
            if (t < (dp[j] >> 3)) {
                float v = __shfl(__int_as_float(em[j].y), t * 8 + g);
                uint4 dd = d[j & 1][t];
                asum += v;
                a0 = fmaf(v, bflo(dd.x), a0);  a1 = fmaf(v, bfhi(dd.x), a1);
                a2 = fmaf(v, bflo(dd.y), a2);  a3 = fmaf(v, bfhi(dd.y), a3);
                a4 = fmaf(v, bflo(dd.z), a4);  a5 = fmaf(v, bfhi(dd.z), a5);
                a6 = fmaf(v, bflo(dd.w), a6);  a7 = fmaf(v, bfhi(dd.w), a7);
            }
        for (int e = rs[j] + 64; e < rs[j] + dp[j]; ++e) {
            int2 ee = ecv[e];
            if (g == 0) {
                float tv = __int_as_float(ee.y);
                uint4 td = *(const uint4*)(dense + (size_t)ee.x + (dq << 3));
                asum += tv;
                a0 = fmaf(tv, bflo(td.x), a0);  a1 = fmaf(tv, bfhi(td.x), a1);
                a2 = fmaf(tv, bflo(td.y), a2);  a3 = fmaf(tv, bfhi(td.y), a3);
                a4 = fmaf(tv, bflo(td.z), a4);  a5 = fmaf(tv, bfhi(td.z), a5);
                a6 = fmaf(tv, bflo(td.w), a6);  a7 = fmaf(tv, bfhi(td.w), a7);
            }
        }
#pragma unroll
        for (int off = 8; off < 64; off <<= 1) {     // reduce edge subgroups (g bits)
            a0 += __shfl_xor(a0, off); a1 += __shfl_xor(a1, off);
            a2 += __shfl_xor(a2, off); a3 += __shfl_xor(a3, off);
            a4 += __shfl_xor(a4, off); a5 += __shfl_xor(a5, off);
            a6 += __shfl_xor(a6, off); a7 += __shfl_xor(a7, off);
            asum += __shfl_xor(asum, off);
        }
        // logits for this lane's dim octet
        float l0 = fmaf(asum, bv0.x, a0) + bc0.x;
        float l1 = fmaf(asum, bv0.y, a1) + bc0.y;
        float l2 = fmaf(asum, bv0.z, a2) + bc0.z;
        float l3 = fmaf(asum, bv0.w, a3) + bc0.w;
        float l4 = fmaf(asum, bv1.x, a4) + bc1.x;
        float l5 = fmaf(asum, bv1.y, a5) + bc1.y;
        float l6 = fmaf(asum, bv1.z, a6) + bc1.z;
        float l7 = fmaf(asum, bv1.w, a7) + bc1.w;
        // log-softmax across the 5 valid octets (dims 0..39), xor over dq bits
        float mx = -1e30f;
        if (dq < 5) {
            mx = fmaxf(fmaxf(fmaxf(l0, l1), fmaxf(l2, l3)),
                       fmaxf(fmaxf(l4, l5), fmaxf(l6, l7)));
        }
#pragma unroll
        for (int off = 1; off < 8; off <<= 1) mx = fmaxf(mx, __shfl_xor(mx, off));
        float s = 0.f;
        if (dq < 5) {
            s = __expf(l0 - mx) + __expf(l1 - mx) + __expf(l2 - mx) + __expf(l3 - mx)
              + __expf(l4 - mx) + __expf(l5 - mx) + __expf(l6 - mx) + __expf(l7 - mx);
        }
#pragma unroll
        for (int off = 1; off < 8; off <<= 1) s += __shfl_xor(s, off);
        float lse = mx + __logf(s);
        if (g == 0 && dq < 5) {
            float4 o0 = {l0 - lse, l1 - lse, l2 - lse, l3 - lse};
            float4 o1 = {l4 - lse, l5 - lse, l6 - lse, l7 - lse};
            float* dst = outF + (size_t)(r0 + j) * N_CLASSES + dq * 8;
            *(float4*)(dst) = o0;
            *(float4*)(dst + 4) = o1;
        }
    }
}

extern "C" void kernel_launch(void* const* d_in, const int* in_sizes, int n_in,
                              void* d_out, int out_size, void* d_ws, size_t ws_size,
                              hipStream_t stream) {
    const float* x    = (const float*)d_in[0];
    const int*   erow = (const int*)  d_in[1];
    const int*   ecol = (const int*)  d_in[2];
    const float* eval = (const float*)d_in[3];
    const float* W1   = (const float*)d_in[4];
    const float* b1   = (const float*)d_in[5];
    const float* W2   = (const float*)d_in[6];
    const float* b2   = (const float*)d_in[7];
    const float* Wc   = (const float*)d_in[8];
    const float* bc   = (const float*)d_in[9];
    float* out = (float*)d_out;

    // ---- workspace layout ----
    char* ws = (char*)d_ws;
    size_t off = 0;
    auto alloc = [&](size_t bytes) { char* p = ws + off; off += (bytes + 255) & ~(size_t)255; return p; };
    unsigned short* bufA = (unsigned short*)alloc((size_t)N_NODES * HID_DIM * sizeof(short)); // 12.8 MB
    unsigned short* bufB = (unsigned short*)alloc((size_t)N_NODES * HID_DIM * sizeof(short)); // 12.8 MB
    int2*  tmp     = (int2*) alloc((size_t)NBUCK * BCAP * sizeof(int2));       // 17.6 MB
    int2*  rowmeta = (int2*) alloc((size_t)N_NODES * sizeof(int2));            // 0.8 MB
    int*   bcnt    = (int*)  alloc(NBUCK * sizeof(int));
    short* W1t     = (short*)alloc((size_t)IN_DIM * HID_DIM * sizeof(short));
    short* Mt      = (short*)alloc((size_t)HID_DIM * HID_DIM * sizeof(short));
    float* bv      = (float*)alloc(64 * sizeof(float));

    const int tile_grid = (N_NODES + 63) / 64;       // 1563
    const int spmm_grid = N_NODES / (4 * RPW);       // 3125 (exact)
    const int grid_a    = (N_EDGES + EPB - 1) / EPB; // 250

    // ---- build bucketed padded CSR (reused by both spmm layers) + weight prep ----
    hipMemsetAsync(bcnt, 0, NBUCK * sizeof(int), stream);
    prep_weights<<<8, 256, 0, stream>>>(W1, W2, Wc, b2, W1t, Mt, bv);
    part_a<<<grid_a, PBLK, 0, stream>>>(erow, ecol, eval, bcnt, tmp);
    part_b<<<NBUCK, 256, 0, stream>>>(bcnt, tmp, rowmeta);

    // ---- layer 1 ----
    gemm1_mfma<<<tile_grid, 256, 0, stream>>>(x, W1t, b1, bufA);
    spmm_csr<<<spmm_grid, 256, 0, stream>>>(rowmeta, tmp, bufA, bufB);
    // ---- layer 2 folded with classifier: u = relu(h)@(W2@Wc), then fused aggregate+softmax ----
    gemm2u_mfma<<<tile_grid, 256, 0, stream>>>(bufB, Mt, bufA);
    spmm_cls<<<spmm_grid, 256, 0, stream>>>(rowmeta, tmp, bufA, bv, bc, out);
}

// Round 10
// 291.390 us; speedup vs baseline: 1.1750x; 1.1750x over previous
//
#include <hip/hip_runtime.h>

#define N_NODES   100000
#define N_EDGES   1600000
#define IN_DIM    128
#define HID_DIM   64
#define N_CLASSES 40

#define NBUCK 782          // ceil(100000 / 128) coarse buckets, bucket = row >> 7
#define BCAP  2816         // bucket capacity incl. pad-to-8
#define EPB   6400         // edges per block in pass A
#define PBLK  1024         // part_a block size

typedef __attribute__((ext_vector_type(8))) short bf16x8;
typedef __attribute__((ext_vector_type(4))) float f32x4;

__device__ inline short f2bf(float f) {
    unsigned u = __float_as_uint(f);
    unsigned r = (u + 0x7FFFu + ((u >> 16) & 1u)) >> 16;   // RNE
    return (short)r;
}
__device__ inline float bflo(unsigned w) { return __uint_as_float(w << 16); }
__device__ inline float bfhi(unsigned w) { return __uint_as_float(w & 0xFFFF0000u); }

// ---------------- weight prep (+ bcnt zero) ----------------
// W1t bf16 [64][128]; Mt = (W2@Wc)^T bf16 [64][64] (rows 40..63 zero); bv = b2@Wc fp32 [40]
__global__ __launch_bounds__(256) void prep_weights(const float* __restrict__ W1,
                                                    const float* __restrict__ W2,
                                                    const float* __restrict__ Wc,
                                                    const float* __restrict__ b2,
                                                    short* __restrict__ W1t,
                                                    short* __restrict__ Mt,
                                                    float* __restrict__ bv,
                                                    int* __restrict__ bcnt) {
    for (int i = blockIdx.x * 256 + threadIdx.x; i < IN_DIM * HID_DIM; i += gridDim.x * 256) {
        int n = i >> 7, k = i & 127;
        W1t[i] = f2bf(W1[k * HID_DIM + n]);
    }
    if (blockIdx.x == 7) {
        for (int i = threadIdx.x; i < NBUCK; i += 256) bcnt[i] = 0;
    }
    if (blockIdx.x == 0) {
        for (int idx = threadIdx.x; idx < HID_DIM * HID_DIM; idx += 256) {
            int n = idx >> 6, i = idx & 63;        // Mt[n][i] = M[i][n] = sum_j W2[i][j]*Wc[j][n]
            float acc = 0.f;
            if (n < N_CLASSES)
                for (int j = 0; j < HID_DIM; ++j)
                    acc = fmaf(W2[i * HID_DIM + j], Wc[j * N_CLASSES + n], acc);
            Mt[n * HID_DIM + i] = f2bf(acc);
        }
        for (int n = threadIdx.x; n < N_CLASSES; n += 256) {
            float acc = 0.f;
            for (int j = 0; j < HID_DIM; ++j)
                acc = fmaf(b2[j], Wc[j * N_CLASSES + n], acc);
            bv[n] = acc;
        }
    }
}

// ---------------- GEMM1 (MFMA): hbf[n,64] = bf16(x[n,128] @ W1 + b1) ----------------
__global__ __launch_bounds__(256) void gemm1_mfma(const float* __restrict__ x,
                                                  const short* __restrict__ W1t,
                                                  const float* __restrict__ b1,
                                                  unsigned short* __restrict__ out) {
    int wave = threadIdx.x >> 6;
    int lane = threadIdx.x & 63;
    int node0 = blockIdx.x * 64 + wave * 16;
    if (node0 >= N_NODES) return;
    int m = lane & 15;
    int q = lane >> 4;
    const float* xrow = x + (size_t)(node0 + m) * IN_DIM;
    f32x4 acc0 = {0,0,0,0}, acc1 = {0,0,0,0}, acc2 = {0,0,0,0}, acc3 = {0,0,0,0};
#pragma unroll
    for (int kb = 0; kb < 4; ++kb) {
        int k0 = kb * 32 + q * 8;
        float4 a0 = *(const float4*)(xrow + k0);
        float4 a1 = *(const float4*)(xrow + k0 + 4);
        bf16x8 af;
        af[0]=f2bf(a0.x); af[1]=f2bf(a0.y); af[2]=f2bf(a0.z); af[3]=f2bf(a0.w);
        af[4]=f2bf(a1.x); af[5]=f2bf(a1.y); af[6]=f2bf(a1.z); af[7]=f2bf(a1.w);
        bf16x8 bf0 = *(const bf16x8*)(W1t + ( 0 + m) * IN_DIM + k0);
        bf16x8 bf1 = *(const bf16x8*)(W1t + (16 + m) * IN_DIM + k0);
        bf16x8 bf2 = *(const bf16x8*)(W1t + (32 + m) * IN_DIM + k0);
        bf16x8 bf3 = *(const bf16x8*)(W1t + (48 + m) * IN_DIM + k0);
        acc0 = __builtin_amdgcn_mfma_f32_16x16x32_bf16(af, bf0, acc0, 0, 0, 0);
        acc1 = __builtin_amdgcn_mfma_f32_16x16x32_bf16(af, bf1, acc1, 0, 0, 0);
        acc2 = __builtin_amdgcn_mfma_f32_16x16x32_bf16(af, bf2, acc2, 0, 0, 0);
        acc3 = __builtin_amdgcn_mfma_f32_16x16x32_bf16(af, bf3, acc3, 0, 0, 0);
    }
    f32x4 accs[4] = {acc0, acc1, acc2, acc3};
#pragma unroll
    for (int t = 0; t < 4; ++t) {
        float bias = b1[t * 16 + m];
#pragma unroll
        for (int r = 0; r < 4; ++r) {
            int node = node0 + q * 4 + r;            // C/D: col=lane&15, row=q*4+r
            out[(size_t)node * HID_DIM + t * 16 + m] = (unsigned short)f2bf(accs[t][r] + bias);
        }
    }
}

// ---------------- GEMM2u (MFMA): u[n,64] = bf16(relu(hbf[n,64]) @ M)  (no bias) ----------------
__global__ __launch_bounds__(256) void gemm2u_mfma(const unsigned short* __restrict__ h,
                                                   const short* __restrict__ Mt,
                                                   unsigned short* __restrict__ out) {
    int wave = threadIdx.x >> 6;
    int lane = threadIdx.x & 63;
    int node0 = blockIdx.x * 64 + wave * 16;
    if (node0 >= N_NODES) return;
    int m = lane & 15;
    int q = lane >> 4;
    const unsigned short* hrow = h + (size_t)(node0 + m) * HID_DIM;
    f32x4 acc0 = {0,0,0,0}, acc1 = {0,0,0,0}, acc2 = {0,0,0,0}, acc3 = {0,0,0,0};
#pragma unroll
    for (int kb = 0; kb < 2; ++kb) {
        int k0 = kb * 32 + q * 8;
        bf16x8 af = *(const bf16x8*)(hrow + k0);
#pragma unroll
        for (int j = 0; j < 8; ++j)
            af[j] = ((unsigned short)af[j] & 0x8000u) ? 0 : af[j];   // bf16 ReLU
        bf16x8 bf0 = *(const bf16x8*)(Mt + ( 0 + m) * HID_DIM + k0);
        bf16x8 bf1 = *(const bf16x8*)(Mt + (16 + m) * HID_DIM + k0);
        bf16x8 bf2 = *(const bf16x8*)(Mt + (32 + m) * HID_DIM + k0);
        bf16x8 bf3 = *(const bf16x8*)(Mt + (48 + m) * HID_DIM + k0);
        acc0 = __builtin_amdgcn_mfma_f32_16x16x32_bf16(af, bf0, acc0, 0, 0, 0);
        acc1 = __builtin_amdgcn_mfma_f32_16x16x32_bf16(af, bf1, acc1, 0, 0, 0);
        acc2 = __builtin_amdgcn_mfma_f32_16x16x32_bf16(af, bf2, acc2, 0, 0, 0);
        acc3 = __builtin_amdgcn_mfma_f32_16x16x32_bf16(af, bf3, acc3, 0, 0, 0);
    }
    f32x4 accs[4] = {acc0, acc1, acc2, acc3};
#pragma unroll
    for (int t = 0; t < 4; ++t) {
#pragma unroll
        for (int r = 0; r < 4; ++r) {
            int node = node0 + q * 4 + r;
            out[(size_t)node * HID_DIM + t * 16 + m] = (unsigned short)f2bf(accs[t][r]);
        }
    }
}

// ---------------- Pass A v3: LDS-staged bucket sort, coalesced write-out ----------------
__global__ __launch_bounds__(PBLK) void part_a(const int* __restrict__ erow,
                                               const int* __restrict__ ecol,
                                               const float* __restrict__ eval,
                                               int* __restrict__ bcnt,
                                               int2* __restrict__ tmp) {
    __shared__ int2 pay[EPB];
    __shared__ unsigned short sbuck[EPB];
    __shared__ int hist[NBUCK], lbase[NBUCK], cur[NBUCK], dofs[NBUCK], scan[NBUCK];
    int e0 = blockIdx.x * EPB;
    int tid = threadIdx.x;
    for (int i = tid; i < NBUCK; i += PBLK) { hist[i] = 0; cur[i] = 0; }
    __syncthreads();
    for (int i = tid; i < EPB; i += PBLK)
        atomicAdd(&hist[erow[e0 + i] >> 7], 1);
    __syncthreads();
    for (int i = tid; i < NBUCK; i += PBLK) {
        int n = hist[i];
        dofs[i] = i * BCAP + (n ? atomicAdd(&bcnt[i], n) : 0);
        scan[i] = n;
    }
    __syncthreads();
    for (int off = 1; off < NBUCK; off <<= 1) {
        int t = 0;
        if (tid < NBUCK && tid >= off) t = scan[tid - off];
        __syncthreads();
        if (tid < NBUCK) scan[tid] += t;
        __syncthreads();
    }
    if (tid < NBUCK) {
        lbase[tid] = scan[tid] - hist[tid];
        dofs[tid] -= lbase[tid];
    }
    __syncthreads();
    for (int i = tid; i < EPB; i += PBLK) {
        int e = e0 + i;
        int r = erow[e];
        int b = r >> 7;
        int p = lbase[b] + atomicAdd(&cur[b], 1);
        pay[p] = make_int2(((r & 127) << 17) | ecol[e], __float_as_int(eval[e]));
        sbuck[p] = (unsigned short)b;
    }
    __syncthreads();
    for (int p = tid; p < EPB; p += PBLK) {
        int b = sbuck[p];
        int dest = dofs[b] + p;
        if (dest < (b + 1) * BCAP)
            tmp[dest] = pay[p];
    }
}

// ---------------- Pass B: sort bucket by local row, pad each row to mult-of-8, col *= 64 ----------------
__global__ __launch_bounds__(256) void part_b(const int* __restrict__ bcnt,
                                              int2* __restrict__ tmp,
                                              int2* __restrict__ rowmeta) {
    __shared__ int2 ein[BCAP];
    __shared__ int2 eout[BCAP];
    __shared__ int hist[128], pad[128], basep[128], cur[128], scan[128];
    int b = blockIdx.x;
    int nb = bcnt[b]; if (nb > BCAP) nb = BCAP;
    for (int i = threadIdx.x; i < nb; i += 256) ein[i] = tmp[(size_t)b * BCAP + i];
    if (threadIdx.x < 128) { hist[threadIdx.x] = 0; cur[threadIdx.x] = 0; }
    __syncthreads();
    for (int i = threadIdx.x; i < nb; i += 256)
        atomicAdd(&hist[(ein[i].x >> 17) & 127], 1);
    __syncthreads();
    if (threadIdx.x < 128) {
        pad[threadIdx.x] = (hist[threadIdx.x] + 7) & ~7;
        scan[threadIdx.x] = pad[threadIdx.x];
    }
    __syncthreads();
    for (int off = 1; off < 128; off <<= 1) {
        int t = 0;
        if (threadIdx.x < 128 && threadIdx.x >= off) t = scan[threadIdx.x - off];
        __syncthreads();
        if (threadIdx.x < 128) scan[threadIdx.x] += t;
        __syncthreads();
    }
    if (threadIdx.x < 128) basep[threadIdx.x] = scan[threadIdx.x] - pad[threadIdx.x];
    __syncthreads();
    int ntot = scan[127]; if (ntot > BCAP) ntot = BCAP;
    for (int i = threadIdx.x; i < nb; i += 256) {
        int lr = (ein[i].x >> 17) & 127;
        int p = basep[lr] + atomicAdd(&cur[lr], 1);
        if (p < BCAP) eout[p] = make_int2((ein[i].x & 0x1FFFF) << 6, ein[i].y);
    }
    __syncthreads();
    if (threadIdx.x < 128) {
        int pe = basep[threadIdx.x] + pad[threadIdx.x];
        for (int p = basep[threadIdx.x] + hist[threadIdx.x]; p < pe && p < BCAP; ++p)
            eout[p] = make_int2(0, 0);
    }
    __syncthreads();
    for (int i = threadIdx.x; i < ntot; i += 256) tmp[(size_t)b * BCAP + i] = eout[i];
    if (threadIdx.x < 128) {
        int r = b * 128 + threadIdx.x;
        if (r < N_NODES)
            rowmeta[r] = make_int2(b * BCAP + basep[threadIdx.x], pad[threadIdx.x]);
    }
}

// ---------------- SpMM v3: one wave per row; all gathers issued upfront ----------------
__global__ __launch_bounds__(256) void spmm_csr(const int2* __restrict__ rowmeta,
                                                const int2* __restrict__ ecv,
                                                const unsigned short* __restrict__ dense,
                                                unsigned short* __restrict__ out) {
    int r = blockIdx.x * 4 + (threadIdx.x >> 6);
    if (r >= N_NODES) return;
    int lane = threadIdx.x & 63;
    int g = lane >> 3, dq = lane & 7;
    int2 meta = rowmeta[r];
    int rs   = __builtin_amdgcn_readfirstlane(meta.x);
    int degp = __builtin_amdgcn_readfirstlane(meta.y);
    float a0=0,a1=0,a2=0,a3=0,a4=0,a5=0,a6=0,a7=0;
    if (degp > 0) {
        int2 em = ecv[rs + (lane < degp ? lane : degp - 1)];
        int iters = degp >> 3; if (iters > 8) iters = 8;
        uint4 d[8];
#pragma unroll
        for (int t = 0; t < 8; ++t) {
            if (t < iters) {
                int col = __shfl(em.x, t * 8 + g);
                d[t] = *(const uint4*)(dense + (size_t)col + (dq << 3));
            }
        }
#pragma unroll
        for (int t = 0; t < 8; ++t) {
            if (t < iters) {
                float v = __shfl(__int_as_float(em.y), t * 8 + g);
                a0 = fmaf(v, bflo(d[t].x), a0);  a1 = fmaf(v, bfhi(d[t].x), a1);
                a2 = fmaf(v, bflo(d[t].y), a2);  a3 = fmaf(v, bfhi(d[t].y), a3);
                a4 = fmaf(v, bflo(d[t].z), a4);  a5 = fmaf(v, bfhi(d[t].z), a5);
                a6 = fmaf(v, bflo(d[t].w), a6);  a7 = fmaf(v, bfhi(d[t].w), a7);
            }
        }
        for (int e = rs + 64; e < rs + degp; ++e) {
            int2 ee = ecv[e];
            if (g == 0) {
                float tv = __int_as_float(ee.y);
                uint4 td = *(const uint4*)(dense + (size_t)ee.x + (dq << 3));
                a0 = fmaf(tv, bflo(td.x), a0);  a1 = fmaf(tv, bfhi(td.x), a1);
                a2 = fmaf(tv, bflo(td.y), a2);  a3 = fmaf(tv, bfhi(td.y), a3);
                a4 = fmaf(tv, bflo(td.z), a4);  a5 = fmaf(tv, bfhi(td.z), a5);
                a6 = fmaf(tv, bflo(td.w), a6);  a7 = fmaf(tv, bfhi(td.w), a7);
            }
        }
    }
#pragma unroll
    for (int off = 8; off < 64; off <<= 1) {
        a0 += __shfl_xor(a0, off); a1 += __shfl_xor(a1, off);
        a2 += __shfl_xor(a2, off); a3 += __shfl_xor(a3, off);
        a4 += __shfl_xor(a4, off); a5 += __shfl_xor(a5, off);
        a6 += __shfl_xor(a6, off); a7 += __shfl_xor(a7, off);
    }
    if (lane < 8) {
        uint4 o;
        o.x = (unsigned short)f2bf(a0) | ((unsigned)(unsigned short)f2bf(a1) << 16);
        o.y = (unsigned short)f2bf(a2) | ((unsigned)(unsigned short)f2bf(a3) << 16);
        o.z = (unsigned short)f2bf(a4) | ((unsigned)(unsigned short)f2bf(a5) << 16);
        o.w = (unsigned short)f2bf(a6) | ((unsigned)(unsigned short)f2bf(a7) << 16);
        *(uint4*)(out + (size_t)r * HID_DIM + lane * 8) = o;
    }
}

// ---------------- SpMM2 + classifier epilogue (v3 body + in-wave log-softmax) ----------------
__global__ __launch_bounds__(256) void spmm_cls(const int2* __restrict__ rowmeta,
                                                const int2* __restrict__ ecv,
                                                const unsigned short* __restrict__ dense,
                                                const float* __restrict__ bv,
                                                const float* __restrict__ bc,
                                                float* __restrict__ outF) {
    int r = blockIdx.x * 4 + (threadIdx.x >> 6);
    if (r >= N_NODES) return;
    int lane = threadIdx.x & 63;
    int g = lane >> 3, dq = lane & 7;
    float4 bv0 = {0,0,0,0}, bv1 = {0,0,0,0}, bc0 = {0,0,0,0}, bc1 = {0,0,0,0};
    if (dq < 5) {
        bv0 = *(const float4*)(bv + dq * 8);  bv1 = *(const float4*)(bv + dq * 8 + 4);
        bc0 = *(const float4*)(bc + dq * 8);  bc1 = *(const float4*)(bc + dq * 8 + 4);
    }
    int2 meta = rowmeta[r];
    int rs   = __builtin_amdgcn_readfirstlane(meta.x);
    int degp = __builtin_amdgcn_readfirstlane(meta.y);
    float a0=0,a1=0,a2=0,a3=0,a4=0,a5=0,a6=0,a7=0, asum=0;
    if (degp > 0) {
        int2 em = ecv[rs + (lane < degp ? lane : degp - 1)];
        int iters = degp >> 3; if (iters > 8) iters = 8;
        uint4 d[8];
#pragma unroll
        for (int t = 0; t < 8; ++t) {
            if (t < iters) {
                int col = __shfl(em.x, t * 8 + g);
                d[t] = *(const uint4*)(dense + (size_t)col + (dq << 3));
            }
        }
#pragma unroll
        for (int t = 0; t < 8; ++t) {
            if (t < iters) {
                float v = __shfl(__int_as_float(em.y), t * 8 + g);
                asum += v;
                a0 = fmaf(v, bflo(d[t].x), a0);  a1 = fmaf(v, bfhi(d[t].x), a1);
                a2 = fmaf(v, bflo(d[t].y), a2);  a3 = fmaf(v, bfhi(d[t].y), a3);
                a4 = fmaf(v, bflo(d[t].z), a4);  a5 = fmaf(v, bfhi(d[t].z), a5);
                a6 = fmaf(v, bflo(d[t].w), a6);  a7 = fmaf(v, bfhi(d[t].w), a7);
            }
        }
        for (int e = rs + 64; e < rs + degp; ++e) {
            int2 ee = ecv[e];
            if (g == 0) {
                float tv = __int_as_float(ee.y);
                uint4 td = *(const uint4*)(dense + (size_t)ee.x + (dq << 3));
                asum += tv;
                a0 = fmaf(tv, bflo(td.x), a0);  a1 = fmaf(tv, bfhi(td.x), a1);
                a2 = fmaf(tv, bflo(td.y), a2);  a3 = fmaf(tv, bfhi(td.y), a3);
                a4 = fmaf(tv, bflo(td.z), a4);  a5 = fmaf(tv, bfhi(td.z), a5);
                a6 = fmaf(tv, bflo(td.w), a6);  a7 = fmaf(tv, bfhi(td.w), a7);
            }
        }
    }
#pragma unroll
    for (int off = 8; off < 64; off <<= 1) {         // reduce over edge subgroups
        a0 += __shfl_xor(a0, off); a1 += __shfl_xor(a1, off);
        a2 += __shfl_xor(a2, off); a3 += __shfl_xor(a3, off);
        a4 += __shfl_xor(a4, off); a5 += __shfl_xor(a5, off);
        a6 += __shfl_xor(a6, off); a7 += __shfl_xor(a7, off);
        asum += __shfl_xor(asum, off);
    }
    // logits for this lane's dim octet (all lanes compute; only dq<5 valid)
    float l0 = fmaf(asum, bv0.x, a0) + bc0.x;
    float l1 = fmaf(asum, bv0.y, a1) + bc0.y;
    float l2 = fmaf(asum, bv0.z, a2) + bc0.z;
    float l3 = fmaf(asum, bv0.w, a3) + bc0.w;
    float l4 = fmaf(asum, bv1.x, a4) + bc1.x;
    float l5 = fmaf(asum, bv1.y, a5) + bc1.y;
    float l6 = fmaf(asum, bv1.z, a6) + bc1.z;
    float l7 = fmaf(asum, bv1.w, a7) + bc1.w;
    float mx = -1e30f;
    if (dq < 5)
        mx = fmaxf(fmaxf(fmaxf(l0, l1), fmaxf(l2, l3)),
                   fmaxf(fmaxf(l4, l5), fmaxf(l6, l7)));
#pragma unroll
    for (int off = 1; off < 8; off <<= 1) mx = fmaxf(mx, __shfl_xor(mx, off));
    float s = 0.f;
    if (dq < 5)
        s = __expf(l0 - mx) + __expf(l1 - mx) + __expf(l2 - mx) + __expf(l3 - mx)
          + __expf(l4 - mx) + __expf(l5 - mx) + __expf(l6 - mx) + __expf(l7 - mx);
#pragma unroll
    for (int off = 1; off < 8; off <<= 1) s += __shfl_xor(s, off);
    float lse = mx + __logf(s);
    if (g == 0 && dq < 5) {
        float4 o0 = {l0 - lse, l1 - lse, l2 - lse, l3 - lse};
        float4 o1 = {l4 - lse, l5 - lse, l6 - lse, l7 - lse};
        float* dst = outF + (size_t)r * N_CLASSES + dq * 8;
        *(float4*)(dst) = o0;
        *(float4*)(dst + 4) = o1;
    }
}

extern "C" void kernel_launch(void* const* d_in, const int* in_sizes, int n_in,
                              void* d_out, int out_size, void* d_ws, size_t ws_size,
                              hipStream_t stream) {
    const float* x    = (const float*)d_in[0];
    const int*   erow = (const int*)  d_in[1];
    const int*   ecol = (const int*)  d_in[2];
    const float* eval = (const float*)d_in[3];
    const float* W1   = (const float*)d_in[4];
    const float* b1   = (const float*)d_in[5];
    const float* W2   = (const float*)d_in[6];
    const float* b2   = (const float*)d_in[7];
    const float* Wc   = (const float*)d_in[8];
    const float* bc   = (const float*)d_in[9];
    float* out = (float*)d_out;

    // ---- workspace layout ----
    char* ws = (char*)d_ws;
    size_t off = 0;
    auto alloc = [&](size_t bytes) { char* p = ws + off; off += (bytes + 255) & ~(size_t)255; return p; };
    unsigned short* bufA = (unsigned short*)alloc((size_t)N_NODES * HID_DIM * sizeof(short)); // 12.8 MB
    unsigned short* bufB = (unsigned short*)alloc((size_t)N_NODES * HID_DIM * sizeof(short)); // 12.8 MB
    int2*  tmp     = (int2*) alloc((size_t)NBUCK * BCAP * sizeof(int2));       // 17.6 MB
    int2*  rowmeta = (int2*) alloc((size_t)N_NODES * sizeof(int2));            // 0.8 MB
    int*   bcnt    = (int*)  alloc(NBUCK * sizeof(int));
    short* W1t     = (short*)alloc((size_t)IN_DIM * HID_DIM * sizeof(short));
    short* Mt      = (short*)alloc((size_t)HID_DIM * HID_DIM * sizeof(short));
    float* bv      = (float*)alloc(64 * sizeof(float));

    const int tile_grid = (N_NODES + 63) / 64;       // 1563
    const int spmm_grid = (N_NODES + 3) / 4;         // 25000
    const int grid_a    = (N_EDGES + EPB - 1) / EPB; // 250

    // ---- build bucketed padded CSR + weight prep (bcnt zeroed inside prep) ----
    prep_weights<<<8, 256, 0, stream>>>(W1, W2, Wc, b2, W1t, Mt, bv, bcnt);
    part_a<<<grid_a, PBLK, 0, stream>>>(erow, ecol, eval, bcnt, tmp);
    part_b<<<NBUCK, 256, 0, stream>>>(bcnt, tmp, rowmeta);

    // ---- layer 1 ----
    gemm1_mfma<<<tile_grid, 256, 0, stream>>>(x, W1t, b1, bufA);
    spmm_csr<<<spmm_grid, 256, 0, stream>>>(rowmeta, tmp, bufA, bufB);
    // ---- layer 2 folded with classifier: u = relu(h)@(W2@Wc); fused aggregate+softmax ----
    gemm2u_mfma<<<tile_grid, 256, 0, stream>>>(bufB, Mt, bufA);
    spmm_cls<<<spmm_grid, 256, 0, stream>>>(rowmeta, tmp, bufA, bv, bc, out);
}

// Round 11
// 268.827 us; speedup vs baseline: 1.2736x; 1.0839x over previous
//
#include <hip/hip_runtime.h>

#define N_NODES   100000
#define N_EDGES   1600000
#define IN_DIM    128
#define HID_DIM   64
#define N_CLASSES 40

#define NBUCK 782          // ceil(100000 / 128) coarse buckets, bucket = row >> 7
#define BCAP  2816         // bucket capacity incl. pad-to-8
#define EPB   6400         // edges per block in pass A
#define PBLK  1024         // part_a block size

typedef __attribute__((ext_vector_type(8))) short bf16x8;
typedef __attribute__((ext_vector_type(4))) float f32x4;

__device__ inline short f2bf(float f) {
    unsigned u = __float_as_uint(f);
    unsigned r = (u + 0x7FFFu + ((u >> 16) & 1u)) >> 16;   // RNE
    return (short)r;
}
__device__ inline float bflo(unsigned w) { return __uint_as_float(w << 16); }
__device__ inline float bfhi(unsigned w) { return __uint_as_float(w & 0xFFFF0000u); }
// packed edge: bits[16:0] = col, bits[31:17] = val as unsigned bf15 (sign dropped, vals >= 0)
__device__ inline float upval(unsigned w) { return __uint_as_float((w >> 17) << 16); }

// ---------------- weight prep (+ bcnt zero) ----------------
// W1t bf16 [64][128]; Mt = (W2@Wc)^T bf16 [64][64] (rows 40..63 zero); bv = b2@Wc fp32 [40]
__global__ __launch_bounds__(256) void prep_weights(const float* __restrict__ W1,
                                                    const float* __restrict__ W2,
                                                    const float* __restrict__ Wc,
                                                    const float* __restrict__ b2,
                                                    short* __restrict__ W1t,
                                                    short* __restrict__ Mt,
                                                    float* __restrict__ bv,
                                                    int* __restrict__ bcnt) {
    for (int i = blockIdx.x * 256 + threadIdx.x; i < IN_DIM * HID_DIM; i += gridDim.x * 256) {
        int n = i >> 7, k = i & 127;
        W1t[i] = f2bf(W1[k * HID_DIM + n]);
    }
    if (blockIdx.x == 7) {
        for (int i = threadIdx.x; i < NBUCK; i += 256) bcnt[i] = 0;
    }
    if (blockIdx.x == 0) {
        for (int idx = threadIdx.x; idx < HID_DIM * HID_DIM; idx += 256) {
            int n = idx >> 6, i = idx & 63;        // Mt[n][i] = M[i][n] = sum_j W2[i][j]*Wc[j][n]
            float acc = 0.f;
            if (n < N_CLASSES)
                for (int j = 0; j < HID_DIM; ++j)
                    acc = fmaf(W2[i * HID_DIM + j], Wc[j * N_CLASSES + n], acc);
            Mt[n * HID_DIM + i] = f2bf(acc);
        }
        for (int n = threadIdx.x; n < N_CLASSES; n += 256) {
            float acc = 0.f;
            for (int j = 0; j < HID_DIM; ++j)
                acc = fmaf(b2[j], Wc[j * N_CLASSES + n], acc);
            bv[n] = acc;
        }
    }
}

// ---------------- GEMM1 (MFMA): hbf[n,64] = bf16(x[n,128] @ W1 + b1) ----------------
__global__ __launch_bounds__(256) void gemm1_mfma(const float* __restrict__ x,
                                                  const short* __restrict__ W1t,
                                                  const float* __restrict__ b1,
                                                  unsigned short* __restrict__ out) {
    int wave = threadIdx.x >> 6;
    int lane = threadIdx.x & 63;
    int node0 = blockIdx.x * 64 + wave * 16;
    if (node0 >= N_NODES) return;
    int m = lane & 15;
    int q = lane >> 4;
    const float* xrow = x + (size_t)(node0 + m) * IN_DIM;
    f32x4 acc0 = {0,0,0,0}, acc1 = {0,0,0,0}, acc2 = {0,0,0,0}, acc3 = {0,0,0,0};
#pragma unroll
    for (int kb = 0; kb < 4; ++kb) {
        int k0 = kb * 32 + q * 8;
        float4 a0 = *(const float4*)(xrow + k0);
        float4 a1 = *(const float4*)(xrow + k0 + 4);
        bf16x8 af;
        af[0]=f2bf(a0.x); af[1]=f2bf(a0.y); af[2]=f2bf(a0.z); af[3]=f2bf(a0.w);
        af[4]=f2bf(a1.x); af[5]=f2bf(a1.y); af[6]=f2bf(a1.z); af[7]=f2bf(a1.w);
        bf16x8 bf0 = *(const bf16x8*)(W1t + ( 0 + m) * IN_DIM + k0);
        bf16x8 bf1 = *(const bf16x8*)(W1t + (16 + m) * IN_DIM + k0);
        bf16x8 bf2 = *(const bf16x8*)(W1t + (32 + m) * IN_DIM + k0);
        bf16x8 bf3 = *(const bf16x8*)(W1t + (48 + m) * IN_DIM + k0);
        acc0 = __builtin_amdgcn_mfma_f32_16x16x32_bf16(af, bf0, acc0, 0, 0, 0);
        acc1 = __builtin_amdgcn_mfma_f32_16x16x32_bf16(af, bf1, acc1, 0, 0, 0);
        acc2 = __builtin_amdgcn_mfma_f32_16x16x32_bf16(af, bf2, acc2, 0, 0, 0);
        acc3 = __builtin_amdgcn_mfma_f32_16x16x32_bf16(af, bf3, acc3, 0, 0, 0);
    }
    f32x4 accs[4] = {acc0, acc1, acc2, acc3};
#pragma unroll
    for (int t = 0; t < 4; ++t) {
        float bias = b1[t * 16 + m];
#pragma unroll
        for (int r = 0; r < 4; ++r) {
            int node = node0 + q * 4 + r;            // C/D: col=lane&15, row=q*4+r
            out[(size_t)node * HID_DIM + t * 16 + m] = (unsigned short)f2bf(accs[t][r] + bias);
        }
    }
}

// ---------------- GEMM2u (MFMA): u[n,64] = bf16(relu(hbf[n,64]) @ M)  (no bias) ----------------
__global__ __launch_bounds__(256) void gemm2u_mfma(const unsigned short* __restrict__ h,
                                                   const short* __restrict__ Mt,
                                                   unsigned short* __restrict__ out) {
    int wave = threadIdx.x >> 6;
    int lane = threadIdx.x & 63;
    int node0 = blockIdx.x * 64 + wave * 16;
    if (node0 >= N_NODES) return;
    int m = lane & 15;
    int q = lane >> 4;
    const unsigned short* hrow = h + (size_t)(node0 + m) * HID_DIM;
    f32x4 acc0 = {0,0,0,0}, acc1 = {0,0,0,0}, acc2 = {0,0,0,0}, acc3 = {0,0,0,0};
#pragma unroll
    for (int kb = 0; kb < 2; ++kb) {
        int k0 = kb * 32 + q * 8;
        bf16x8 af = *(const bf16x8*)(hrow + k0);
#pragma unroll
        for (int j = 0; j < 8; ++j)
            af[j] = ((unsigned short)af[j] & 0x8000u) ? 0 : af[j];   // bf16 ReLU
        bf16x8 bf0 = *(const bf16x8*)(Mt + ( 0 + m) * HID_DIM + k0);
        bf16x8 bf1 = *(const bf16x8*)(Mt + (16 + m) * HID_DIM + k0);
        bf16x8 bf2 = *(const bf16x8*)(Mt + (32 + m) * HID_DIM + k0);
        bf16x8 bf3 = *(const bf16x8*)(Mt + (48 + m) * HID_DIM + k0);
        acc0 = __builtin_amdgcn_mfma_f32_16x16x32_bf16(af, bf0, acc0, 0, 0, 0);
        acc1 = __builtin_amdgcn_mfma_f32_16x16x32_bf16(af, bf1, acc1, 0, 0, 0);
        acc2 = __builtin_amdgcn_mfma_f32_16x16x32_bf16(af, bf2, acc2, 0, 0, 0);
        acc3 = __builtin_amdgcn_mfma_f32_16x16x32_bf16(af, bf3, acc3, 0, 0, 0);
    }
    f32x4 accs[4] = {acc0, acc1, acc2, acc3};
#pragma unroll
    for (int t = 0; t < 4; ++t) {
#pragma unroll
        for (int r = 0; r < 4; ++r) {
            int node = node0 + q * 4 + r;
            out[(size_t)node * HID_DIM + t * 16 + m] = (unsigned short)f2bf(accs[t][r]);
        }
    }
}

// ---------------- Pass A v3: LDS-staged bucket sort, coalesced write-out ----------------
__global__ __launch_bounds__(PBLK) void part_a(const int* __restrict__ erow,
                                               const int* __restrict__ ecol,
                                               const float* __restrict__ eval,
                                               int* __restrict__ bcnt,
                                               int2* __restrict__ tmp) {
    __shared__ int2 pay[EPB];
    __shared__ unsigned short sbuck[EPB];
    __shared__ int hist[NBUCK], lbase[NBUCK], cur[NBUCK], dofs[NBUCK], scan[NBUCK];
    int e0 = blockIdx.x * EPB;
    int tid = threadIdx.x;
    for (int i = tid; i < NBUCK; i += PBLK) { hist[i] = 0; cur[i] = 0; }
    __syncthreads();
    for (int i = tid; i < EPB; i += PBLK)
        atomicAdd(&hist[erow[e0 + i] >> 7], 1);
    __syncthreads();
    for (int i = tid; i < NBUCK; i += PBLK) {
        int n = hist[i];
        dofs[i] = i * BCAP + (n ? atomicAdd(&bcnt[i], n) : 0);
        scan[i] = n;
    }
    __syncthreads();
    for (int off = 1; off < NBUCK; off <<= 1) {
        int t = 0;
        if (tid < NBUCK && tid >= off) t = scan[tid - off];
        __syncthreads();
        if (tid < NBUCK) scan[tid] += t;
        __syncthreads();
    }
    if (tid < NBUCK) {
        lbase[tid] = scan[tid] - hist[tid];
        dofs[tid] -= lbase[tid];
    }
    __syncthreads();
    for (int i = tid; i < EPB; i += PBLK) {
        int e = e0 + i;
        int r = erow[e];
        int b = r >> 7;
        int p = lbase[b] + atomicAdd(&cur[b], 1);
        pay[p] = make_int2(((r & 127) << 17) | ecol[e], __float_as_int(eval[e]));
        sbuck[p] = (unsigned short)b;
    }
    __syncthreads();
    for (int p = tid; p < EPB; p += PBLK) {
        int b = sbuck[p];
        int dest = dofs[b] + p;
        if (dest < (b + 1) * BCAP)
            tmp[dest] = pay[p];
    }
}

// ---------------- Pass B: sort bucket by local row, pad to mult-of-8, pack to 4 B ----------------
__global__ __launch_bounds__(256) void part_b(const int* __restrict__ bcnt,
                                              const int2* __restrict__ tmp,
                                              unsigned* __restrict__ tmp2,
                                              int2* __restrict__ rowmeta) {
    __shared__ int2 ein[BCAP];           // 22.5 KB
    __shared__ unsigned eout[BCAP];      // 11.3 KB
    __shared__ int hist[128], pad[128], basep[128], cur[128], scan[128];
    int b = blockIdx.x;
    int nb = bcnt[b]; if (nb > BCAP) nb = BCAP;
    for (int i = threadIdx.x; i < nb; i += 256) ein[i] = tmp[(size_t)b * BCAP + i];
    if (threadIdx.x < 128) { hist[threadIdx.x] = 0; cur[threadIdx.x] = 0; }
    __syncthreads();
    for (int i = threadIdx.x; i < nb; i += 256)
        atomicAdd(&hist[(ein[i].x >> 17) & 127], 1);
    __syncthreads();
    if (threadIdx.x < 128) {
        pad[threadIdx.x] = (hist[threadIdx.x] + 7) & ~7;
        scan[threadIdx.x] = pad[threadIdx.x];
    }
    __syncthreads();
    for (int off = 1; off < 128; off <<= 1) {
        int t = 0;
        if (threadIdx.x < 128 && threadIdx.x >= off) t = scan[threadIdx.x - off];
        __syncthreads();
        if (threadIdx.x < 128) scan[threadIdx.x] += t;
        __syncthreads();
    }
    if (threadIdx.x < 128) basep[threadIdx.x] = scan[threadIdx.x] - pad[threadIdx.x];
    __syncthreads();
    int ntot = scan[127]; if (ntot > BCAP) ntot = BCAP;
    for (int i = threadIdx.x; i < nb; i += 256) {
        int lr = (ein[i].x >> 17) & 127;
        int p = basep[lr] + atomicAdd(&cur[lr], 1);
        if (p < BCAP) {
            unsigned u = (unsigned)ein[i].y;
            unsigned vb = ((u + 0x7FFFu + ((u >> 16) & 1u)) >> 16) & 0x7FFFu; // bf15 RNE, sign dropped
            eout[p] = (vb << 17) | (unsigned)(ein[i].x & 0x1FFFF);
        }
    }
    __syncthreads();
    if (threadIdx.x < 128) {
        int pe = basep[threadIdx.x] + pad[threadIdx.x];
        for (int p = basep[threadIdx.x] + hist[threadIdx.x]; p < pe && p < BCAP; ++p)
            eout[p] = 0u;                 // col 0, val +0.0
    }
    __syncthreads();
    for (int i = threadIdx.x; i < ntot; i += 256) tmp2[(size_t)b * BCAP + i] = eout[i];
    if (threadIdx.x < 128) {
        int r = b * 128 + threadIdx.x;
        if (r < N_NODES)
            rowmeta[r] = make_int2(b * BCAP + basep[threadIdx.x], pad[threadIdx.x]);
    }
}

// ---------------- SpMM v5: one row per 8-lane subgroup, LDS meta staging, no shuffles ----------------
// lane = (s = lane>>3: row within wave, dq = lane&7: dim octet). 16 B/lane gathers.
__global__ __launch_bounds__(256) void spmm_csr(const int2* __restrict__ rowmeta,
                                                const unsigned* __restrict__ ecv,
                                                const unsigned short* __restrict__ dense,
                                                unsigned short* __restrict__ out) {
    __shared__ unsigned lm[4][8][68];    // 8.7 KB; stride 68 words: 16B-aligned rows, <=2-way banks
    int wave = threadIdx.x >> 6;
    int lane = threadIdx.x & 63;
    int s = lane >> 3, dq = lane & 7;
    int r = (blockIdx.x * 4 + wave) * 8 + s;   // 3125 * 4 * 8 == 100000
    int2 meta = rowmeta[r];
    int beg = meta.x, deg = meta.y;            // deg multiple of 8 (maybe 0)
    int degc = deg < 64 ? deg : 64;
    for (int e = dq; e < degc; e += 8)         // stage this row's packed edges
        lm[wave][s][e] = ecv[beg + e];
    __syncthreads();
    const unsigned* mp = lm[wave][s];
    float a0=0,a1=0,a2=0,a3=0,a4=0,a5=0,a6=0,a7=0;
    if (deg > 0) {
        uint4 w = *(const uint4*)mp;           // deg>0 => deg>=8, safe
        for (int e = 0; e < degc; e += 4) {
            uint4 wn = (e + 4 < degc) ? *(const uint4*)(mp + e + 4) : w;   // 1-ahead meta (lgkm)
            uint4 g0 = *(const uint4*)(dense + ((size_t)(w.x & 0x1FFFF) << 6) + (dq << 3));
            uint4 g1 = *(const uint4*)(dense + ((size_t)(w.y & 0x1FFFF) << 6) + (dq << 3));
            uint4 g2 = *(const uint4*)(dense + ((size_t)(w.z & 0x1FFFF) << 6) + (dq << 3));
            uint4 g3 = *(const uint4*)(dense + ((size_t)(w.w & 0x1FFFF) << 6) + (dq << 3));
            float v0 = upval(w.x), v1 = upval(w.y), v2 = upval(w.z), v3 = upval(w.w);
            a0=fmaf(v0,bflo(g0.x),a0); a1=fmaf(v0,bfhi(g0.x),a1); a2=fmaf(v0,bflo(g0.y),a2); a3=fmaf(v0,bfhi(g0.y),a3);
            a4=fmaf(v0,bflo(g0.z),a4); a5=fmaf(v0,bfhi(g0.z),a5); a6=fmaf(v0,bflo(g0.w),a6); a7=fmaf(v0,bfhi(g0.w),a7);
            a0=fmaf(v1,bflo(g1.x),a0); a1=fmaf(v1,bfhi(g1.x),a1); a2=fmaf(v1,bflo(g1.y),a2); a3=fmaf(v1,bfhi(g1.y),a3);
            a4=fmaf(v1,bflo(g1.z),a4); a5=fmaf(v1,bfhi(g1.z),a5); a6=fmaf(v1,bflo(g1.w),a6); a7=fmaf(v1,bfhi(g1.w),a7);
            a0=fmaf(v2,bflo(g2.x),a0); a1=fmaf(v2,bfhi(g2.x),a1); a2=fmaf(v2,bflo(g2.y),a2); a3=fmaf(v2,bfhi(g2.y),a3);
            a4=fmaf(v2,bflo(g2.z),a4); a5=fmaf(v2,bfhi(g2.z),a5); a6=fmaf(v2,bflo(g2.w),a6); a7=fmaf(v2,bfhi(g2.w),a7);
            a0=fmaf(v3,bflo(g3.x),a0); a1=fmaf(v3,bfhi(g3.x),a1); a2=fmaf(v3,bflo(g3.y),a2); a3=fmaf(v3,bfhi(g3.y),a3);
            a4=fmaf(v3,bflo(g3.z),a4); a5=fmaf(v3,bfhi(g3.z),a5); a6=fmaf(v3,bflo(g3.w),a6); a7=fmaf(v3,bfhi(g3.w),a7);
            w = wn;
        }
        for (int e = 64; e < deg; ++e) {       // rare tail (deg > 64)
            unsigned we = ecv[beg + e];
            uint4 g = *(const uint4*)(dense + ((size_t)(we & 0x1FFFF) << 6) + (dq << 3));
            float v = upval(we);
            a0=fmaf(v,bflo(g.x),a0); a1=fmaf(v,bfhi(g.x),a1); a2=fmaf(v,bflo(g.y),a2); a3=fmaf(v,bfhi(g.y),a3);
            a4=fmaf(v,bflo(g.z),a4); a5=fmaf(v,bfhi(g.z),a5); a6=fmaf(v,bflo(g.w),a6); a7=fmaf(v,bfhi(g.w),a7);
        }
    }
    uint4 o;
    o.x = (unsigned short)f2bf(a0) | ((unsigned)(unsigned short)f2bf(a1) << 16);
    o.y = (unsigned short)f2bf(a2) | ((unsigned)(unsigned short)f2bf(a3) << 16);
    o.z = (unsigned short)f2bf(a4) | ((unsigned)(unsigned short)f2bf(a5) << 16);
    o.w = (unsigned short)f2bf(a6) | ((unsigned)(unsigned short)f2bf(a7) << 16);
    *(uint4*)(out + (size_t)r * HID_DIM + (dq << 3)) = o;
}

// ---------------- SpMM2 + classifier epilogue (v5 body + intra-subgroup log-softmax) ----------------
__global__ __launch_bounds__(256) void spmm_cls(const int2* __restrict__ rowmeta,
                                                const unsigned* __restrict__ ecv,
                                                const unsigned short* __restrict__ dense,
                                                const float* __restrict__ bv,
                                                const float* __restrict__ bc,
                                                float* __restrict__ outF) {
    __shared__ unsigned lm[4][8][68];
    int wave = threadIdx.x >> 6;
    int lane = threadIdx.x & 63;
    int s = lane >> 3, dq = lane & 7;
    int r = (blockIdx.x * 4 + wave) * 8 + s;
    float4 bv0 = {0,0,0,0}, bv1 = {0,0,0,0}, bc0 = {0,0,0,0}, bc1 = {0,0,0,0};
    if (dq < 5) {
        bv0 = *(const float4*)(bv + dq * 8);  bv1 = *(const float4*)(bv + dq * 8 + 4);
        bc0 = *(const float4*)(bc + dq * 8);  bc1 = *(const float4*)(bc + dq * 8 + 4);
    }
    int2 meta = rowmeta[r];
    int beg = meta.x, deg = meta.y;
    int degc = deg < 64 ? deg : 64;
    for (int e = dq; e < degc; e += 8)
        lm[wave][s][e] = ecv[beg + e];
    __syncthreads();
    const unsigned* mp = lm[wave][s];
    float a0=0,a1=0,a2=0,a3=0,a4=0,a5=0,a6=0,a7=0, asum=0;
    if (deg > 0) {
        uint4 w = *(const uint4*)mp;
        for (int e = 0; e < degc; e += 4) {
            uint4 wn = (e + 4 < degc) ? *(const uint4*)(mp + e + 4) : w;
            uint4 g0 = *(const uint4*)(dense + ((size_t)(w.x & 0x1FFFF) << 6) + (dq << 3));
            uint4 g1 = *(const uint4*)(dense + ((size_t)(w.y & 0x1FFFF) << 6) + (dq << 3));
            uint4 g2 = *(const uint4*)(dense + ((size_t)(w.z & 0x1FFFF) << 6) + (dq << 3));
            uint4 g3 = *(const uint4*)(dense + ((size_t)(w.w & 0x1FFFF) << 6) + (dq << 3));
            float v0 = upval(w.x), v1 = upval(w.y), v2 = upval(w.z), v3 = upval(w.w);
            asum += v0 + v1 + v2 + v3;
            a0=fmaf(v0,bflo(g0.x),a0); a1=fmaf(v0,bfhi(g0.x),a1); a2=fmaf(v0,bflo(g0.y),a2); a3=fmaf(v0,bfhi(g0.y),a3);
            a4=fmaf(v0,bflo(g0.z),a4); a5=fmaf(v0,bfhi(g0.z),a5); a6=fmaf(v0,bflo(g0.w),a6); a7=fmaf(v0,bfhi(g0.w),a7);
            a0=fmaf(v1,bflo(g1.x),a0); a1=fmaf(v1,bfhi(g1.x),a1); a2=fmaf(v1,bflo(g1.y),a2); a3=fmaf(v1,bfhi(g1.y),a3);
            a4=fmaf(v1,bflo(g1.z),a4); a5=fmaf(v1,bfhi(g1.z),a5); a6=fmaf(v1,bflo(g1.w),a6); a7=fmaf(v1,bfhi(g1.w),a7);
            a0=fmaf(v2,bflo(g2.x),a0); a1=fmaf(v2,bfhi(g2.x),a1); a2=fmaf(v2,bflo(g2.y),a2); a3=fmaf(v2,bfhi(g2.y),a3);
            a4=fmaf(v2,bflo(g2.z),a4); a5=fmaf(v2,bfhi(g2.z),a5); a6=fmaf(v2,bflo(g2.w),a6); a7=fmaf(v2,bfhi(g2.w),a7);
            a0=fmaf(v3,bflo(g3.x),a0); a1=fmaf(v3,bfhi(g3.x),a1); a2=fmaf(v3,bflo(g3.y),a2); a3=fmaf(v3,bfhi(g3.y),a3);
            a4=fmaf(v3,bflo(g3.z),a4); a5=fmaf(v3,bfhi(g3.z),a5); a6=fmaf(v3,bflo(g3.w),a6); a7=fmaf(v3,bfhi(g3.w),a7);
            w = wn;
        }
        for (int e = 64; e < deg; ++e) {
            unsigned we = ecv[beg + e];
            uint4 g = *(const uint4*)(dense + ((size_t)(we & 0x1FFFF) << 6) + (dq << 3));
            float v = upval(we);
            asum += v;
            a0=fmaf(v,bflo(g.x),a0); a1=fmaf(v,bfhi(g.x),a1); a2=fmaf(v,bflo(g.y),a2); a3=fmaf(v,bfhi(g.y),a3);
            a4=fmaf(v,bflo(g.z),a4); a5=fmaf(v,bfhi(g.z),a5); a6=fmaf(v,bflo(g.w),a6); a7=fmaf(v,bfhi(g.w),a7);
        }
    }
    // logits for this lane's dim octet (asum is complete per-lane; no reduction needed)
    float l0 = fmaf(asum, bv0.x, a0) + bc0.x;
    float l1 = fmaf(asum, bv0.y, a1) + bc0.y;
    float l2 = fmaf(asum, bv0.z, a2) + bc0.z;
    float l3 = fmaf(asum, bv0.w, a3) + bc0.w;
    float l4 = fmaf(asum, bv1.x, a4) + bc1.x;
    float l5 = fmaf(asum, bv1.y, a5) + bc1.y;
    float l6 = fmaf(asum, bv1.z, a6) + bc1.z;
    float l7 = fmaf(asum, bv1.w, a7) + bc1.w;
    float mx = -1e30f;
    if (dq < 5)
        mx = fmaxf(fmaxf(fmaxf(l0, l1), fmaxf(l2, l3)),
                   fmaxf(fmaxf(l4, l5), fmaxf(l6, l7)));
#pragma unroll
    for (int off = 1; off < 8; off <<= 1) mx = fmaxf(mx, __shfl_xor(mx, off));
    float ss = 0.f;
    if (dq < 5)
        ss = __expf(l0 - mx) + __expf(l1 - mx) + __expf(l2 - mx) + __expf(l3 - mx)
           + __expf(l4 - mx) + __expf(l5 - mx) + __expf(l6 - mx) + __expf(l7 - mx);
#pragma unroll
    for (int off = 1; off < 8; off <<= 1) ss += __shfl_xor(ss, off);
    float lse = mx + __logf(ss);
    if (dq < 5) {
        float4 o0 = {l0 - lse, l1 - lse, l2 - lse, l3 - lse};
        float4 o1 = {l4 - lse, l5 - lse, l6 - lse, l7 - lse};
        float* dst = outF + (size_t)r * N_CLASSES + dq * 8;
        *(float4*)(dst) = o0;
        *(float4*)(dst + 4) = o1;
    }
}

extern "C" void kernel_launch(void* const* d_in, const int* in_sizes, int n_in,
                              void* d_out, int out_size, void* d_ws, size_t ws_size,
                              hipStream_t stream) {
    const float* x    = (const float*)d_in[0];
    const int*   erow = (const int*)  d_in[1];
    const int*   ecol = (const int*)  d_in[2];
    const float* eval = (const float*)d_in[3];
    const float* W1   = (const float*)d_in[4];
    const float* b1   = (const float*)d_in[5];
    const float* W2   = (const float*)d_in[6];
    const float* b2   = (const float*)d_in[7];
    const float* Wc   = (const float*)d_in[8];
    const float* bc   = (const float*)d_in[9];
    float* out = (float*)d_out;

    // ---- workspace layout ----
    char* ws = (char*)d_ws;
    size_t off = 0;
    auto alloc = [&](size_t bytes) { char* p = ws + off; off += (bytes + 255) & ~(size_t)255; return p; };
    unsigned short* bufA = (unsigned short*)alloc((size_t)N_NODES * HID_DIM * sizeof(short)); // 12.8 MB
    unsigned short* bufB = (unsigned short*)alloc((size_t)N_NODES * HID_DIM * sizeof(short)); // 12.8 MB
    int2*     tmp     = (int2*)    alloc((size_t)NBUCK * BCAP * sizeof(int2));     // 17.6 MB
    unsigned* tmp2    = (unsigned*)alloc((size_t)NBUCK * BCAP * sizeof(unsigned)); //  8.8 MB
    int2*     rowmeta = (int2*)    alloc((size_t)N_NODES * sizeof(int2));          //  0.8 MB
    int*      bcnt    = (int*)     alloc(NBUCK * sizeof(int));
    short*    W1t     = (short*)   alloc((size_t)IN_DIM * HID_DIM * sizeof(short));
    short*    Mt      = (short*)   alloc((size_t)HID_DIM * HID_DIM * sizeof(short));
    float*    bv      = (float*)   alloc(64 * sizeof(float));

    const int tile_grid = (N_NODES + 63) / 64;       // 1563
    const int spmm_grid = N_NODES / 32;              // 3125 (4 waves x 8 rows, exact)
    const int grid_a    = (N_EDGES + EPB - 1) / EPB; // 250

    // ---- build bucketed packed CSR + weight prep (bcnt zeroed inside prep) ----
    prep_weights<<<8, 256, 0, stream>>>(W1, W2, Wc, b2, W1t, Mt, bv, bcnt);
    part_a<<<grid_a, PBLK, 0, stream>>>(erow, ecol, eval, bcnt, tmp);
    part_b<<<NBUCK, 256, 0, stream>>>(bcnt, tmp, tmp2, rowmeta);

    // ---- layer 1 ----
    gemm1_mfma<<<tile_grid, 256, 0, stream>>>(x, W1t, b1, bufA);
    spmm_csr<<<spmm_grid, 256, 0, stream>>>(rowmeta, tmp2, bufA, bufB);
    // ---- layer 2 folded with classifier: u = relu(h)@(W2@Wc); fused aggregate+softmax ----
    gemm2u_mfma<<<tile_grid, 256, 0, stream>>>(bufB, Mt, bufA);
    spmm_cls<<<spmm_grid, 256, 0, stream>>>(rowmeta, tmp2, bufA, bv, bc, out);
}